// Round 23
// baseline (15782.492 us; speedup 1.0000x reference)
//
#include <hip/hip_runtime.h>
#include <math.h>

#define B_ 32
#define T_ 512
#define D_ 1024
#define H_ 1024
#define L_ 4
#define RPW 40                 // reduce row stride (floats): 160 B, 4-way max on b128
#define PACK_PER_BLK 32768     // 16 cols x 2048 k floats = 128 KB per block

typedef unsigned long long u64;

// Cross-XCD state access: agent-scope relaxed atomics (sc1) hit the MALL
// coherence point directly. No fences anywhere -> XCD L2s never invalidated.
__device__ __forceinline__ float4 load_state4(const float* p) {
    u64 a = __hip_atomic_load((const u64*)p,       __ATOMIC_RELAXED, __HIP_MEMORY_SCOPE_AGENT);
    u64 b = __hip_atomic_load((const u64*)(p + 2), __ATOMIC_RELAXED, __HIP_MEMORY_SCOPE_AGENT);
    float4 v;
    v.x = __uint_as_float((unsigned)(a & 0xffffffffu));
    v.y = __uint_as_float((unsigned)(a >> 32));
    v.z = __uint_as_float((unsigned)(b & 0xffffffffu));
    v.w = __uint_as_float((unsigned)(b >> 32));
    return v;
}

// Poll: fast no-sleep spin first, then throttled s_sleep(2).
// Timeout + always-release => no hang, no cascade.
__device__ __forceinline__ void waitCount(const unsigned int* p, unsigned int target) {
    for (int c = 0; c < 256; ++c)
        if (__hip_atomic_load(p, __ATOMIC_RELAXED, __HIP_MEMORY_SCOPE_AGENT) >= target)
            return;
    int c = 0;
    while (__hip_atomic_load(p, __ATOMIC_RELAXED, __HIP_MEMORY_SCOPE_AGENT) < target) {
        __builtin_amdgcn_s_sleep(2);
        if (++c > 200000) return;   // ~10 ms cap per dependency
    }
}

// One-time weight repack (proven R18): Wpack[bid][col16][k2048].
__global__ __launch_bounds__(512) void lnn_repack(
    const float* __restrict__ W_in, const float* __restrict__ W_h,
    float* __restrict__ Wpack)
{
    const int bid   = blockIdx.x;
    const int layer = bid >> 6;
    const int jbase = (bid & 63) << 4;
    const float* Win_l = W_in + (size_t)layer * D_ * H_;
    const float* Wh_l  = W_h  + (size_t)layer * H_ * H_;
    float* dst = Wpack + (size_t)bid * PACK_PER_BLK;
#pragma unroll 1
    for (int i = 0; i < 16; ++i) {
        const int f  = (i << 9) + threadIdx.x;   // float4 index 0..8191
        const int d  = f << 2;
        const int jj = d >> 11;
        const int k  = d & 2047;                 // k..k+3 stay in one half
        const float* s = (k < 1024) ? &Win_l[(size_t)k * H_ + jbase + jj]
                                    : &Wh_l[(size_t)(k - 1024) * H_ + jbase + jj];
        float4 v;
        v.x = s[0];
        v.y = s[(size_t)H_];
        v.z = s[(size_t)2 * H_];
        v.w = s[(size_t)3 * H_];
        *(float4*)&dst[d] = v;
    }
}

// Reduce phase, LITERAL P (rule #20). Phase P covers absolute rows 8P..8P+7.
// Writers: the 256 threads whose batch-half bh == P>>1 dump acc[rloc..rloc+7]
// (4 cols each) into padded LDS; readers: 128 threads sum 64 kslot partials,
// tanh/tau, sc1-store.
#define REDUCE_PHASE(P)                                                         \
    do {                                                                        \
        constexpr int bhp  = (P) >> 1;                                          \
        constexpr int rloc = ((P) & 1) << 3;                                    \
        __syncthreads();                                                        \
        if (bh == bhp) {                                                        \
            const int wrow = (kslot << 2) + jq;                                 \
            _Pragma("unroll")                                                   \
            for (int q = 0; q < 8; ++q)                                         \
                *(float4*)&red[wrow * RPW + (q << 2)] = acc[rloc + q];          \
        }                                                                       \
        __syncthreads();                                                        \
        if (tid < 128) {                                                        \
            const int bo   = tid >> 4;            /* row within phase */        \
            const int bhat = ((P) << 3) + bo;     /* absolute batch row */      \
            const int jhat = tid & 15;                                          \
            const int sj   = jhat >> 2;           /* source jq */               \
            const int cc   = jhat & 3;            /* col within quad */         \
            float s = 0.f;                                                      \
            _Pragma("unroll")                                                   \
            for (int ks = 0; ks < 64; ++ks)                                     \
                s += red[((ks << 2) + sj) * RPW + (bo << 2) + cc];              \
            const float dx   = tanhf(s + bias);                                 \
            const float hold = __hip_atomic_load(&hrow[(size_t)bhat * H_ + jr], \
                                __ATOMIC_RELAXED, __HIP_MEMORY_SCOPE_AGENT);    \
            const float hn   = hold + (dx - hold) / tv;                         \
            __hip_atomic_store(&wl[(size_t)bhat * H_ + jr], hn,                 \
                               __ATOMIC_RELAXED, __HIP_MEMORY_SCOPE_AGENT);     \
        }                                                                       \
    } while (0)

// Persistent kernel: 256 blocks (1/CU), 512 threads.
// R23 vs R21 (single partition change; R22's tile reorder REVERTED):
//   thread = (jq: 4-col quad) x (bh: 16-row batch half) x (kslot: 64).
//   One ds_read_b128 now feeds 16 FMAs (was 8) -> compute DS reads halve
//   (R21 budget showed the LDS pipe ~12.7 us was the largest floor term).
//   Weight requests duplicate x2 across batch halves — working set unchanged
//   (4 MB/XCD, L2-resident), so HBM FETCH should hold.
// HARD RULES kept: tile loop ROLLED (unroll 1; full unroll spills past the
// immovable 128-VGPR cap), reduce indices literal, sc1 state protocol,
// p2p layer-neighbor sync (R21).
template<bool PACKED>
__global__ __launch_bounds__(512, 2) void lnn_persist(
    const float* __restrict__ x,      // [B][T][D]
    const float* __restrict__ W_in,   // [L][D][H]
    const float* __restrict__ b_in,   // [L][H]
    const float* __restrict__ W_h,    // [L][H][H]
    const float* __restrict__ b_h,    // [L][H]
    const float* __restrict__ tau,    // [L][H]
    const float* __restrict__ Wpack,  // [256][PACK_PER_BLK] repacked weights
    float* __restrict__ buf0,         // [L][B][H] state, parity 0
    float* __restrict__ buf1,         // [L][B][H] state, parity 1
    unsigned int* __restrict__ done)  // [L][T_] per-(layer,timestep) counters
{
    const int tid   = threadIdx.x;
    const int layer = blockIdx.x >> 6;
    const int jbase = (blockIdx.x & 63) << 4;
    const int jq    = tid & 3;        // col quad: cols jbase+4jq .. +3
    const int bh    = (tid >> 2) & 1; // batch half: rows 16bh .. 16bh+15
    const int kslot = tid >> 3;       // 0..63
    const int kb    = kslot << 2;     // k offset within 256-tile (floats)

    __shared__ __align__(16) float smem[16384];     // 64 KB: xs[2][32][256]
    float (*xs)[32][256] = (float(*)[32][256])smem;
    float* red = smem;                               // reduce aliases (41 KB)

    const float* Wl_in = W_in + (size_t)layer * D_ * H_;
    const float* Wl_h  = W_h  + (size_t)layer * H_ * H_;
    // 4 packed column streams for this thread's col quad
    const float* wb0 = Wpack + (size_t)blockIdx.x * PACK_PER_BLK
                     + ((size_t)((jq << 2) + 0) << 11);
    const float* wb1 = wb0 + 2048;
    const float* wb2 = wb0 + 4096;
    const float* wb3 = wb0 + 6144;
    const int jgA = jbase + (jq << 2);

    // reduce-reader per-thread constants (role: jhat = tid & 15)
    const int   jr   = jbase + (tid & 15);
    const float bias = b_in[layer * H_ + jr] + b_h[layer * H_ + jr];
    const float tv   = tau[layer * H_ + jr];

    // staging role: e = q*512 + tid -> row e>>6, float4-col e&63
    const int srow = tid >> 6;
    const int scol = (tid & 63) << 2;

    for (int t = 0; t < T_; ++t) {
        if (tid == 0) {
            if (layer > 0)             waitCount(&done[(layer - 1) * T_ + t],       64u);
            if (t >= 1)                waitCount(&done[layer * T_ + (t - 1)],       64u);
            if (layer < 3 && t >= 2)   waitCount(&done[(layer + 1) * T_ + (t - 2)], 64u);
        }
        __syncthreads();   // all threads ordered after the waits

        const int par = (t + layer) & 1;            // global-tick parity
        const float* rb   = par ? buf0 : buf1;      // state at t-1
        float*       wb   = par ? buf1 : buf0;      // state at t
        const float* hrow = rb + (size_t)layer * B_ * H_;
        float*       wl   = wb + (size_t)layer * B_ * H_;

        const float* xsrc; size_t xstr;
        if (layer == 0) { xsrc = x + (size_t)t * D_;                  xstr = (size_t)T_ * D_; }
        else            { xsrc = rb + (size_t)(layer - 1) * B_ * H_;  xstr = H_; }

        float4 acc[16];
#pragma unroll
        for (int i = 0; i < 16; ++i) acc[i] = make_float4(0.f, 0.f, 0.f, 0.f);

        // ---- prologue: stage tile 0 into xs[0] ----
        {
            const bool at0 = (layer != 0);
#pragma unroll
            for (int q = 0; q < 4; ++q) {
                const int r = srow + (q << 3);
                const float* sp = &xsrc[(size_t)r * xstr + scol];
                float4 v = at0 ? load_state4(sp) : *(const float4*)sp;
                *(float4*)&xs[0][r][scol] = v;
            }
        }
        __syncthreads();

#pragma unroll 1
        for (int tile = 0; tile < 8; ++tile) {
            const int cur = tile & 1;

            // (1) this tile's weights FIRST (FMAs wait only on these):
            //     4 cols x 4 k = 4 contiguous dwordx4 from the packed streams
            float4 w0, w1, w2, w3;
            if constexpr (PACKED) {
                w0 = *(const float4*)&wb0[(tile << 8) + kb];
                w1 = *(const float4*)&wb1[(tile << 8) + kb];
                w2 = *(const float4*)&wb2[(tile << 8) + kb];
                w3 = *(const float4*)&wb3[(tile << 8) + kb];
            } else {
                const int kof = (tile & 3) << 8;
                const float* wp = ((tile < 4) ? Wl_in : Wl_h)
                                + (size_t)(kof + kb) * H_ + jgA;
                w0.x = wp[0];              w1.x = wp[1];
                w0.y = wp[(size_t)H_];     w1.y = wp[(size_t)H_ + 1];
                w0.z = wp[2*(size_t)H_];   w1.z = wp[2*(size_t)H_ + 1];
                w0.w = wp[3*(size_t)H_];   w1.w = wp[3*(size_t)H_ + 1];
                w2.x = wp[2];              w3.x = wp[3];
                w2.y = wp[(size_t)H_ + 2]; w3.y = wp[(size_t)H_ + 3];
                w2.z = wp[2*(size_t)H_+2]; w3.z = wp[2*(size_t)H_ + 3];
                w2.w = wp[3*(size_t)H_+2]; w3.w = wp[3*(size_t)H_ + 3];
            }

            // (2) issue NEXT tile's staging loads (latency hides under (3))
            float4 stg[4];
            if (tile < 7) {
                const int    nt   = tile + 1;
                const float* nsrc = (nt < 4) ? xsrc : hrow;
                const size_t nstr = (nt < 4) ? xstr : (size_t)H_;
                const int    nkof = (nt & 3) << 8;
                const bool   nat  = (nt >= 4) || (layer != 0);
#pragma unroll
                for (int q = 0; q < 4; ++q) {
                    const int r = srow + (q << 3);
                    const float* sp = &nsrc[(size_t)r * nstr + nkof + scol];
                    stg[q] = nat ? load_state4(sp) : *(const float4*)sp;
                }
            }

            // (3) compute this tile: 16 rows x {1 ds_read_b128 + 16 FMA}
#pragma unroll
            for (int r = 0; r < 16; ++r) {
                const int row = (bh << 4) + r;
                const float4 a = *(const float4*)&xs[cur][row][kb];
                acc[r].x += a.x * w0.x + a.y * w0.y + a.z * w0.z + a.w * w0.w;
                acc[r].y += a.x * w1.x + a.y * w1.y + a.z * w1.z + a.w * w1.w;
                acc[r].z += a.x * w2.x + a.y * w2.y + a.z * w2.z + a.w * w2.w;
                acc[r].w += a.x * w3.x + a.y * w3.y + a.z * w3.z + a.w * w3.w;
            }

            // (4) write staged regs to the other buffer; ONE barrier/tile
            if (tile < 7) {
#pragma unroll
                for (int q = 0; q < 4; ++q)
                    *(float4*)&xs[cur ^ 1][srow + (q << 3)][scol] = stg[q];
            }
            __syncthreads();
        }

        // ---- k-reduction: 4 phases, literal indices (rule #20) ----
        REDUCE_PHASE(0); REDUCE_PHASE(1); REDUCE_PHASE(2); REDUCE_PHASE(3);

        // __syncthreads() drains every wave's vmem ops (s_waitcnt vmcnt(0)
        // before s_barrier) -> all sc1 stores at MALL before the release-add.
        __syncthreads();
        if (tid == 0)
            __hip_atomic_fetch_add(&done[layer * T_ + t], 1u,
                                   __ATOMIC_RELEASE, __HIP_MEMORY_SCOPE_AGENT);
    }
}

// out[b][o] = sum_k h3[b][k] * W_out[k][o] + b_out[o]   (validated rounds 0-22)
__global__ __launch_bounds__(256) void lnn_out(
    const float* __restrict__ H3,     // [B][H]
    const float* __restrict__ W_out,  // [H][O]
    const float* __restrict__ b_out,  // [O]
    float* __restrict__ out)          // [B][O]
{
    const int gid = blockIdx.x * 256 + threadIdx.x;  // 64 blocks -> 16384 threads
    const int jj  = gid & 1023;
    const int b2  = gid >> 10;                       // 0..15 -> rows b2, b2+16
    float acc0 = b_out[jj];
    float acc1 = b_out[jj];
    for (int k = 0; k < H_; ++k) {
        const float w = W_out[k * H_ + jj];
        acc0 += H3[b2 * H_ + k]        * w;
        acc1 += H3[(b2 + 16) * H_ + k] * w;
    }
    out[b2 * H_ + jj]        = acc0;
    out[(b2 + 16) * H_ + jj] = acc1;
}

extern "C" void kernel_launch(void* const* d_in, const int* in_sizes, int n_in,
                              void* d_out, int out_size, void* d_ws, size_t ws_size,
                              hipStream_t stream) {
    const float* x     = (const float*)d_in[0];
    const float* W_in  = (const float*)d_in[1];
    const float* b_in  = (const float*)d_in[2];
    const float* W_h   = (const float*)d_in[3];
    const float* b_h   = (const float*)d_in[4];
    const float* tau   = (const float*)d_in[5];
    const float* W_out = (const float*)d_in[6];
    const float* b_out = (const float*)d_in[7];

    const size_t stateElems = (size_t)L_ * B_ * H_;          // 131072 floats
    const size_t packElems  = (size_t)256 * PACK_PER_BLK;    // 32 MB
    const size_t cntDwords  = (size_t)L_ * T_;               // 2048 counters
    const size_t needPacked = (packElems + 2 * stateElems) * sizeof(float)
                            + cntDwords * sizeof(unsigned int);
    const bool packed = (ws_size >= needPacked);

    float* Wpack = (float*)d_ws;
    float* buf0  = packed ? (Wpack + packElems) : (float*)d_ws;
    float* buf1  = buf0 + stateElems;
    unsigned int* done = (unsigned int*)(buf1 + stateElems);

    // zero state + done counters (captured in graph -> reset every replay)
    (void)hipMemsetAsync(buf0, 0,
                         2 * stateElems * sizeof(float) + cntDwords * sizeof(unsigned int),
                         stream);

    if (packed) {
        lnn_repack<<<256, 512, 0, stream>>>(W_in, W_h, Wpack);
        lnn_persist<true><<<256, 512, 0, stream>>>(x, W_in, b_in, W_h, b_h, tau,
                                                   Wpack, buf0, buf1, done);
    } else {
        lnn_persist<false><<<256, 512, 0, stream>>>(x, W_in, b_in, W_h, b_h, tau,
                                                    Wpack, buf0, buf1, done);
    }

    // h3 at t=511: parity (511+3)&1 = 0 -> written into buf0.
    // Kernel boundary provides coherence for these plain loads.
    const float* H3 = buf0 + 3 * (B_ * H_);
    lnn_out<<<64, 256, 0, stream>>>(H3, W_out, b_out, (float*)d_out);
}

// Round 24
// 13301.395 us; speedup vs baseline: 1.1865x; 1.1865x over previous
//
#include <hip/hip_runtime.h>
#include <math.h>

#define B_ 32
#define T_ 512
#define D_ 1024
#define H_ 1024
#define L_ 4
#define RPD 17                 // reduce row pad (floats)
#define PACK_PER_BLK 32768     // 16 cols x 2048 k floats = 128 KB per block

typedef unsigned long long u64;

// Cross-XCD state access: agent-scope relaxed atomics (sc1) hit the MALL
// coherence point directly. No fences anywhere -> XCD L2s never invalidated.
__device__ __forceinline__ float4 load_state4(const float* p) {
    u64 a = __hip_atomic_load((const u64*)p,       __ATOMIC_RELAXED, __HIP_MEMORY_SCOPE_AGENT);
    u64 b = __hip_atomic_load((const u64*)(p + 2), __ATOMIC_RELAXED, __HIP_MEMORY_SCOPE_AGENT);
    float4 v;
    v.x = __uint_as_float((unsigned)(a & 0xffffffffu));
    v.y = __uint_as_float((unsigned)(a >> 32));
    v.z = __uint_as_float((unsigned)(b & 0xffffffffu));
    v.w = __uint_as_float((unsigned)(b >> 32));
    return v;
}

// Relaxed spin + s_sleep throttle; short timeout + always-release => no hang.
// (R21's proven form; R22/R23's unthrottled fast-path spin is a suspected
// MALL-congestion confounder and is NOT used.)
__device__ __forceinline__ void waitCount(const unsigned int* p, unsigned int target) {
    int c = 0;
    while (__hip_atomic_load(p, __ATOMIC_RELAXED, __HIP_MEMORY_SCOPE_AGENT) < target) {
        __builtin_amdgcn_s_sleep(16);
        if (++c > 20000) return;   // ~4 ms cap per dependency
    }
}

// One-time weight repack (proven R18): Wpack[bid][col16][k2048].
__global__ __launch_bounds__(512) void lnn_repack(
    const float* __restrict__ W_in, const float* __restrict__ W_h,
    float* __restrict__ Wpack)
{
    const int bid   = blockIdx.x;
    const int layer = bid >> 6;
    const int jbase = (bid & 63) << 4;
    const float* Win_l = W_in + (size_t)layer * D_ * H_;
    const float* Wh_l  = W_h  + (size_t)layer * H_ * H_;
    float* dst = Wpack + (size_t)bid * PACK_PER_BLK;
#pragma unroll 1
    for (int i = 0; i < 16; ++i) {
        const int f  = (i << 9) + threadIdx.x;   // float4 index 0..8191
        const int d  = f << 2;
        const int jj = d >> 11;
        const int k  = d & 2047;                 // k..k+3 stay in one half
        const float* s = (k < 1024) ? &Win_l[(size_t)k * H_ + jbase + jj]
                                    : &Wh_l[(size_t)(k - 1024) * H_ + jbase + jj];
        float4 v;
        v.x = s[0];
        v.y = s[(size_t)H_];
        v.z = s[(size_t)2 * H_];
        v.w = s[(size_t)3 * H_];
        *(float4*)&dst[d] = v;
    }
}

// Reduce phase with LITERAL P (rule #20) — proven R19/R21.
#define REDUCE_PHASE(P)                                                         \
    do {                                                                        \
        __syncthreads();                                                        \
        _Pragma("unroll")                                                       \
        for (int q = 0; q < 8; ++q) {                                           \
            red[tid * RPD + (q << 1)]     = acc[((P) << 3) + q].x;              \
            red[tid * RPD + (q << 1) + 1] = acc[((P) << 3) + q].y;              \
        }                                                                       \
        __syncthreads();                                                        \
        if (tid < 128) {                                                        \
            const int bo   = tid >> 4;                                          \
            const int bh   = ((P) << 3) + bo;                                   \
            const int js   = (tid & 15) >> 1;                                   \
            const int comp = tid & 1;                                           \
            float s = 0.f;                                                      \
            _Pragma("unroll")                                                   \
            for (int ks = 0; ks < 64; ++ks)                                     \
                s += red[((ks << 3) + js) * RPD + (bo << 1) + comp];            \
            const float dx   = tanhf(s + bias);                                 \
            const float hold = __hip_atomic_load(&hrow[(size_t)bh * H_ + jr],   \
                                __ATOMIC_RELAXED, __HIP_MEMORY_SCOPE_AGENT);    \
            const float hn   = hold + (dx - hold) / tv;                         \
            __hip_atomic_store(&wl[(size_t)bh * H_ + jr], hn,                   \
                               __ATOMIC_RELAXED, __HIP_MEMORY_SCOPE_AGENT);     \
        }                                                                       \
    } while (0)

// Persistent kernel: 256 blocks (1/CU), 512 threads = 8 j-pairs x 64 kslots.
// R24 = BYTE-FOR-BYTE REVERT to R21 (13.3 ms, session best). R22 (wait
// hiding), R23 (4-col partition) both regressed; R20 (sub-counters) was null.
// Conclusion carried in-code: no pipe is binding (VALU 24%, DS slack with
// 0-conflict variant SLOWER, HBM 8%) — the period is the dependency chain +
// sync latency; this structure is its measured minimum.
// HARD RULES: tile loop ROLLED (unroll 1; full unroll spills past the
// immovable 128-VGPR cap for 512-thread blocks), reduce indices literal,
// sc1 state protocol, p2p layer-neighbor sync.
template<bool PACKED>
__global__ __launch_bounds__(512, 2) void lnn_persist(
    const float* __restrict__ x,      // [B][T][D]
    const float* __restrict__ W_in,   // [L][D][H]
    const float* __restrict__ b_in,   // [L][H]
    const float* __restrict__ W_h,    // [L][H][H]
    const float* __restrict__ b_h,    // [L][H]
    const float* __restrict__ tau,    // [L][H]
    const float* __restrict__ Wpack,  // [256][PACK_PER_BLK] repacked weights
    float* __restrict__ buf0,         // [L][B][H] state, parity 0
    float* __restrict__ buf1,         // [L][B][H] state, parity 1
    unsigned int* __restrict__ done)  // [L][T_] per-(layer,timestep) counters
{
    const int tid   = threadIdx.x;
    const int layer = blockIdx.x >> 6;
    const int jbase = (blockIdx.x & 63) << 4;
    const int jp    = tid & 7;        // j-pair: cols jbase+2jp, +1
    const int kslot = tid >> 3;       // 0..63
    const int kb    = kslot << 2;     // k offset within 256-tile (floats)

    __shared__ __align__(16) float smem[16384];     // 64 KB: xs[2][32][256]
    float (*xs)[32][256] = (float(*)[32][256])smem;
    float* red = smem;                               // reduce aliases (34.8 KB)

    const float* Wl_in = W_in + (size_t)layer * D_ * H_;
    const float* Wl_h  = W_h  + (size_t)layer * H_ * H_;
    const float* wbaseA = Wpack + (size_t)blockIdx.x * PACK_PER_BLK
                        + ((size_t)(jp << 1) << 11);
    const float* wbaseB = wbaseA + 2048;
    const int jgA = jbase + (jp << 1);

    // reduce-reader per-thread constants (role: jhat = tid & 15)
    const int   jr   = jbase + (tid & 15);
    const float bias = b_in[layer * H_ + jr] + b_h[layer * H_ + jr];
    const float tv   = tau[layer * H_ + jr];

    // staging role: e = q*512 + tid -> row e>>6, float4-col e&63
    const int srow = tid >> 6;
    const int scol = (tid & 63) << 2;

    for (int t = 0; t < T_; ++t) {
        if (tid == 0) {
            if (layer > 0)             waitCount(&done[(layer - 1) * T_ + t],     64u);
            if (t >= 1)                waitCount(&done[layer * T_ + (t - 1)],     64u);
            if (layer < 3 && t >= 2)   waitCount(&done[(layer + 1) * T_ + (t - 2)], 64u);
        }
        __syncthreads();   // all threads ordered after the waits

        const int par = (t + layer) & 1;            // global-tick parity
        const float* rb   = par ? buf0 : buf1;      // state at t-1
        float*       wb   = par ? buf1 : buf0;      // state at t
        const float* hrow = rb + (size_t)layer * B_ * H_;
        float*       wl   = wb + (size_t)layer * B_ * H_;

        const float* xsrc; size_t xstr;
        if (layer == 0) { xsrc = x + (size_t)t * D_;                  xstr = (size_t)T_ * D_; }
        else            { xsrc = rb + (size_t)(layer - 1) * B_ * H_;  xstr = H_; }

        float2 acc[32];
#pragma unroll
        for (int i = 0; i < 32; ++i) acc[i] = make_float2(0.f, 0.f);

        // ---- prologue: stage tile 0 into xs[0] ----
        {
            const bool at0 = (layer != 0);
#pragma unroll
            for (int q = 0; q < 4; ++q) {
                const int r = srow + (q << 3);
                const float* sp = &xsrc[(size_t)r * xstr + scol];
                float4 v = at0 ? load_state4(sp) : *(const float4*)sp;
                *(float4*)&xs[0][r][scol] = v;
            }
        }
        __syncthreads();

#pragma unroll 1
        for (int tile = 0; tile < 8; ++tile) {
            const int cur = tile & 1;

            // (1) this tile's weights FIRST (FMAs wait only on these)
            float4 wA, wB;
            if constexpr (PACKED) {
                wA = *(const float4*)&wbaseA[(tile << 8) + kb];
                wB = *(const float4*)&wbaseB[(tile << 8) + kb];
            } else {
                const int kof = (tile & 3) << 8;
                const float* wp = ((tile < 4) ? Wl_in : Wl_h)
                                + (size_t)(kof + kb) * H_ + jgA;
                wA.x = wp[0];            wB.x = wp[1];
                wA.y = wp[(size_t)H_];   wB.y = wp[(size_t)H_ + 1];
                wA.z = wp[2*(size_t)H_]; wB.z = wp[2*(size_t)H_ + 1];
                wA.w = wp[3*(size_t)H_]; wB.w = wp[3*(size_t)H_ + 1];
            }

            // (2) issue NEXT tile's staging loads (latency hides under (3))
            float4 stg[4];
            if (tile < 7) {
                const int    nt   = tile + 1;
                const float* nsrc = (nt < 4) ? xsrc : hrow;
                const size_t nstr = (nt < 4) ? xstr : (size_t)H_;
                const int    nkof = (nt & 3) << 8;
                const bool   nat  = (nt >= 4) || (layer != 0);
#pragma unroll
                for (int q = 0; q < 4; ++q) {
                    const int r = srow + (q << 3);
                    const float* sp = &nsrc[(size_t)r * nstr + nkof + scol];
                    stg[q] = nat ? load_state4(sp) : *(const float4*)sp;
                }
            }

            // (3) compute this tile: 32 rows x {1 ds_read_b128 + 8 FMA}
#pragma unroll
            for (int b = 0; b < 32; ++b) {
                const float4 a = *(const float4*)&xs[cur][b][kb];
                acc[b].x += a.x * wA.x + a.y * wA.y + a.z * wA.z + a.w * wA.w;
                acc[b].y += a.x * wB.x + a.y * wB.y + a.z * wB.z + a.w * wB.w;
            }

            // (4) write staged regs to the other buffer; ONE barrier/tile
            if (tile < 7) {
#pragma unroll
                for (int q = 0; q < 4; ++q)
                    *(float4*)&xs[cur ^ 1][srow + (q << 3)][scol] = stg[q];
            }
            __syncthreads();
        }

        // ---- k-reduction: 4 phases, literal indices (rule #20) ----
        REDUCE_PHASE(0); REDUCE_PHASE(1); REDUCE_PHASE(2); REDUCE_PHASE(3);

        // __syncthreads() drains every wave's vmem ops (s_waitcnt vmcnt(0)
        // before s_barrier) -> all sc1 stores at MALL before the release-add.
        __syncthreads();
        if (tid == 0)
            __hip_atomic_fetch_add(&done[layer * T_ + t], 1u,
                                   __ATOMIC_RELEASE, __HIP_MEMORY_SCOPE_AGENT);
    }
}

// out[b][o] = sum_k h3[b][k] * W_out[k][o] + b_out[o]   (validated rounds 0-23)
__global__ __launch_bounds__(256) void lnn_out(
    const float* __restrict__ H3,     // [B][H]
    const float* __restrict__ W_out,  // [H][O]
    const float* __restrict__ b_out,  // [O]
    float* __restrict__ out)          // [B][O]
{
    const int gid = blockIdx.x * 256 + threadIdx.x;  // 64 blocks -> 16384 threads
    const int jj  = gid & 1023;
    const int b2  = gid >> 10;                       // 0..15 -> rows b2, b2+16
    float acc0 = b_out[jj];
    float acc1 = b_out[jj];
    for (int k = 0; k < H_; ++k) {
        const float w = W_out[k * H_ + jj];
        acc0 += H3[b2 * H_ + k]        * w;
        acc1 += H3[(b2 + 16) * H_ + k] * w;
    }
    out[b2 * H_ + jj]        = acc0;
    out[(b2 + 16) * H_ + jj] = acc1;
}

extern "C" void kernel_launch(void* const* d_in, const int* in_sizes, int n_in,
                              void* d_out, int out_size, void* d_ws, size_t ws_size,
                              hipStream_t stream) {
    const float* x     = (const float*)d_in[0];
    const float* W_in  = (const float*)d_in[1];
    const float* b_in  = (const float*)d_in[2];
    const float* W_h   = (const float*)d_in[3];
    const float* b_h   = (const float*)d_in[4];
    const float* tau   = (const float*)d_in[5];
    const float* W_out = (const float*)d_in[6];
    const float* b_out = (const float*)d_in[7];

    const size_t stateElems = (size_t)L_ * B_ * H_;          // 131072 floats
    const size_t packElems  = (size_t)256 * PACK_PER_BLK;    // 32 MB
    const size_t cntDwords  = (size_t)L_ * T_;               // 2048 counters
    const size_t needPacked = (packElems + 2 * stateElems) * sizeof(float)
                            + cntDwords * sizeof(unsigned int);
    const bool packed = (ws_size >= needPacked);

    float* Wpack = (float*)d_ws;
    float* buf0  = packed ? (Wpack + packElems) : (float*)d_ws;
    float* buf1  = buf0 + stateElems;
    unsigned int* done = (unsigned int*)(buf1 + stateElems);

    // zero state + done counters (captured in graph -> reset every replay)
    (void)hipMemsetAsync(buf0, 0,
                         2 * stateElems * sizeof(float) + cntDwords * sizeof(unsigned int),
                         stream);

    if (packed) {
        lnn_repack<<<256, 512, 0, stream>>>(W_in, W_h, Wpack);
        lnn_persist<true><<<256, 512, 0, stream>>>(x, W_in, b_in, W_h, b_h, tau,
                                                   Wpack, buf0, buf1, done);
    } else {
        lnn_persist<false><<<256, 512, 0, stream>>>(x, W_in, b_in, W_h, b_h, tau,
                                                    Wpack, buf0, buf1, done);
    }

    // h3 at t=511: parity (511+3)&1 = 0 -> written into buf0.
    // Kernel boundary provides coherence for these plain loads.
    const float* H3 = buf0 + 3 * (B_ * H_);
    lnn_out<<<64, 256, 0, stream>>>(H3, W_out, b_out, (float*)d_out);
}